// Round 2
// baseline (121.278 us; speedup 1.0000x reference)
//
#include <hip/hip_runtime.h>

#define NBUCKETS 4096   // top 12 bits of order-preserving float key
#define FIN_THREADS 1024
#define BPT (NBUCKETS / FIN_THREADS)  // buckets per thread in finalize = 4

// ---------------------------------------------------------------------------
// K1: per-block LDS histogram of hinge errors.
//   key = order-preserving u32 map of f32 error (larger e -> larger key)
//   bucket = key >> 20
//   h[b]: low32 = count, high32 = positive count (packed, one u64 LDS atomic)
//   s[b]: sum of error values (f32 LDS atomic)
// ---------------------------------------------------------------------------
__global__ __launch_bounds__(1024) void lovasz_hist(
    const float* __restrict__ logits, const int* __restrict__ targets,
    unsigned long long* __restrict__ g_hist, double* __restrict__ g_sum,
    unsigned int* __restrict__ g_maxkey, int n)
{
    __shared__ unsigned long long h[NBUCKETS];  // 32 KB
    __shared__ float s[NBUCKETS];               // 16 KB
    __shared__ unsigned int smax;

    const int tid = threadIdx.x;
    for (int i = tid; i < NBUCKETS; i += blockDim.x) { h[i] = 0ULL; s[i] = 0.0f; }
    if (tid == 0) smax = 0u;
    __syncthreads();

    unsigned int lmax = 0u;
    const long long gthreads = (long long)gridDim.x * blockDim.x;
    const long long gid = (long long)blockIdx.x * blockDim.x + tid;
    const long long stride = gthreads * 4;

#define PROC(lv, tv) {                                                     \
        float e = (tv) ? (1.0f - (lv)) : (1.0f + (lv));                    \
        unsigned u = __float_as_uint(e);                                   \
        unsigned key = (u & 0x80000000u) ? ~u : (u | 0x80000000u);         \
        unsigned b = key >> 20;                                            \
        atomicAdd(&h[b], 1ULL | ((unsigned long long)((tv) != 0) << 32));  \
        atomicAdd(&s[b], e);                                               \
        if (key > lmax) lmax = key; }

    for (long long i = gid * 4; i + 3 < (long long)n; i += stride) {
        const float4 L = *reinterpret_cast<const float4*>(logits + i);
        const int4  T = *reinterpret_cast<const int4*>(targets + i);
        PROC(L.x, T.x) PROC(L.y, T.y) PROC(L.z, T.z) PROC(L.w, T.w)
    }
    // scalar tail (n not multiple of 4)
    for (long long j = (long long)(n & ~3) + gid; j < (long long)n; j += gthreads) {
        float lv = logits[j]; int tv = targets[j];
        PROC(lv, tv)
    }
#undef PROC

    atomicMax(&smax, lmax);
    __syncthreads();

    // flush only non-empty buckets
    for (int b = tid; b < NBUCKETS; b += blockDim.x) {
        unsigned long long hv = h[b];
        if (hv) atomicAdd(&g_hist[b], hv);
        float sv = s[b];
        if (sv != 0.0f) atomicAdd(&g_sum[b], (double)sv);
    }
    if (tid == 0) atomicMax(g_maxkey, smax);
}

// ---------------------------------------------------------------------------
// K2: single block. Suffix-scan counts over buckets (descending value order),
// midpoint-ratio dot over ALL buckets (reference effectively applies grad to
// every sorted error, negative included), grad[0] correction, scalar out.
//   F(b)  = # elements in strictly-greater buckets
//   tau_b = (I - Fp - p_b/2) / (n - F - c_b/2)     (midpoint within bucket)
//   out   = sum_b S_b * tau_b  -  e_max * I / n
// ---------------------------------------------------------------------------
__global__ __launch_bounds__(FIN_THREADS) void lovasz_final(
    const unsigned long long* __restrict__ g_hist, const double* __restrict__ g_sum,
    const unsigned int* __restrict__ g_maxkey, float* __restrict__ out, int n)
{
    const int t = threadIdx.x;
    __shared__ unsigned int sc[FIN_THREADS], sp[FIN_THREADS];
    __shared__ double sd[FIN_THREADS];

    unsigned c[BPT], p[BPT];
    double sv[BPT];
    unsigned ct = 0, pt = 0;
    for (int k = 0; k < BPT; ++k) {
        unsigned long long hv = g_hist[t * BPT + k];
        c[k] = (unsigned)(hv & 0xFFFFFFFFULL);
        p[k] = (unsigned)(hv >> 32);
        sv[k] = g_sum[t * BPT + k];
        ct += c[k]; pt += p[k];
    }
    sc[t] = ct; sp[t] = pt;
    __syncthreads();

    // inclusive suffix scan over thread partials (Hillis-Steele)
    for (int off = 1; off < FIN_THREADS; off <<= 1) {
        unsigned a = (t + off < FIN_THREADS) ? sc[t + off] : 0u;
        unsigned b = (t + off < FIN_THREADS) ? sp[t + off] : 0u;
        __syncthreads();
        sc[t] += a; sp[t] += b;
        __syncthreads();
    }

    const unsigned I = sp[0];                 // total positives (intersection)
    const double dn = (double)n;
    const double dI = (double)I;

    unsigned F  = sc[t] - ct;                 // exclusive suffix (threads > t)
    unsigned Fp = sp[t] - pt;
    double acc = 0.0;
    for (int k = BPT - 1; k >= 0; --k) {      // high bucket -> low within thread
        if (c[k]) {
            const double tau = (dI - (double)Fp - 0.5 * (double)p[k])
                             / (dn - (double)F - 0.5 * (double)c[k]);
            acc += sv[k] * tau;
        }
        F += c[k]; Fp += p[k];
    }

    sd[t] = acc;
    __syncthreads();
    for (int off = FIN_THREADS / 2; off > 0; off >>= 1) {
        if (t < off) sd[t] += sd[t + off];
        __syncthreads();
    }

    if (t == 0) {
        // grad[0] = 0 in the reference: remove the top element's approximated
        // contribution (it was included at tau_top ~= I/n).
        unsigned mk = *g_maxkey;
        unsigned mu = (mk & 0x80000000u) ? (mk & 0x7FFFFFFFu) : ~mk;
        float emax = __uint_as_float(mu);
        double corr = (double)emax * dI / dn;
        out[0] = (float)(sd[0] - corr);
    }
}

extern "C" void kernel_launch(void* const* d_in, const int* in_sizes, int n_in,
                              void* d_out, int out_size, void* d_ws, size_t ws_size,
                              hipStream_t stream)
{
    const float* logits  = (const float*)d_in[0];
    const int*   targets = (const int*)d_in[1];
    const int n = in_sizes[0];

    unsigned long long* g_hist = (unsigned long long*)d_ws;
    double* g_sum = (double*)((char*)d_ws + (size_t)NBUCKETS * 8);
    unsigned int* g_maxkey = (unsigned int*)((char*)d_ws + (size_t)NBUCKETS * 16);

    // zero hist + sums + maxkey every call (graph-capturable memset node)
    hipMemsetAsync(d_ws, 0, (size_t)NBUCKETS * 16 + 256, stream);

    hipLaunchKernelGGL(lovasz_hist, dim3(512), dim3(1024), 0, stream,
                       logits, targets, g_hist, g_sum, g_maxkey, n);
    hipLaunchKernelGGL(lovasz_final, dim3(1), dim3(1024), 0, stream,
                       g_hist, g_sum, g_maxkey, (float*)d_out, n);
}

// Round 3
// 43.373 us; speedup vs baseline: 2.7962x; 2.7962x over previous
//
#include <hip/hip_runtime.h>

#define VBUCKETS 2048          // 11-bit order-preserving float key
#define NCOPIES 2              // LDS histogram copies (by wave parity)
#define HSIZE (NCOPIES * 2 * VBUCKETS)   // copies x classes x vbuckets
#define FIN_THREADS 1024
#define BPT (VBUCKETS / FIN_THREADS)     // = 2

// ws layout: g_cnt u32[2*VBUCKETS] | g_sum u64[2*VBUCKETS] | g_maxkey u32
#define CNT_BYTES (2 * VBUCKETS * 4)
#define SUM_BYTES (2 * VBUCKETS * 8)

// ---------------------------------------------------------------------------
// K1: privatized LDS histogram, ONE packed ds_add_u64 per element.
//   entry = (count << 44) | fixedpoint_sum(|e| * 2^24)
//   idx   = (copy<<12) | (class<<11) | (key>>21)
// ---------------------------------------------------------------------------
__global__ __launch_bounds__(1024) void lovasz_hist(
    const float* __restrict__ logits, const int* __restrict__ targets,
    unsigned int* __restrict__ g_cnt, unsigned long long* __restrict__ g_sum,
    unsigned int* __restrict__ g_maxkey, int n)
{
    __shared__ unsigned long long h[HSIZE];   // 64 KB
    __shared__ unsigned int smax;

    const int tid = threadIdx.x;
    for (int i = tid; i < HSIZE; i += blockDim.x) h[i] = 0ULL;
    if (tid == 0) smax = 0u;
    __syncthreads();

    const unsigned copyBase = ((tid >> 6) & (NCOPIES - 1)) << 12;
    unsigned int lmax = 0u;
    const long long gthreads = (long long)gridDim.x * blockDim.x;
    const long long gid = (long long)blockIdx.x * blockDim.x + tid;
    const long long stride = gthreads * 4;

#define PROC(lv, tv) {                                                        \
        float e = (tv) ? (1.0f - (lv)) : (1.0f + (lv));                       \
        unsigned u = __float_as_uint(e);                                      \
        unsigned key = (u & 0x80000000u) ? ~u : (u | 0x80000000u);            \
        unsigned idx = copyBase | (((unsigned)((tv) != 0)) << 11) | (key >> 21); \
        unsigned sfix = (unsigned)(fabsf(e) * 16777216.0f);                   \
        atomicAdd(&h[idx], (1ULL << 44) | (unsigned long long)sfix);          \
        if (key > lmax) lmax = key; }

    for (long long i = gid * 4; i + 3 < (long long)n; i += stride) {
        const float4 L = *reinterpret_cast<const float4*>(logits + i);
        const int4  T = *reinterpret_cast<const int4*>(targets + i);
        PROC(L.x, T.x) PROC(L.y, T.y) PROC(L.z, T.z) PROC(L.w, T.w)
    }
    for (long long j = (long long)(n & ~3) + gid; j < (long long)n; j += gthreads) {
        float lv = logits[j]; int tv = targets[j];
        PROC(lv, tv)
    }
#undef PROC

    // wave-reduce max key, one LDS atomic per wave
    for (int off = 32; off > 0; off >>= 1) {
        unsigned o = (unsigned)__shfl_xor((int)lmax, off);
        if (o > lmax) lmax = o;
    }
    if ((tid & 63) == 0) atomicMax(&smax, lmax);
    __syncthreads();

    // merge copy1 into copy0 (no atomics needed after barrier)
    for (int i = tid; i < 2 * VBUCKETS; i += blockDim.x)
        h[i] += h[i + (1 << 12)];
    __syncthreads();

    // flush non-empty entries: unpack -> separate global count / sum atomics
    for (int i = tid; i < 2 * VBUCKETS; i += blockDim.x) {
        unsigned long long hv = h[i];
        if (hv) {
            atomicAdd(&g_cnt[i], (unsigned)(hv >> 44));
            atomicAdd(&g_sum[i], hv & ((1ULL << 44) - 1ULL));
        }
    }
    if (tid == 0) atomicMax(g_maxkey, smax);
}

// ---------------------------------------------------------------------------
// K2: single block. Suffix scan over buckets (descending value order),
// midpoint-ratio dot over ALL buckets, grad[0] correction, scalar out.
//   c_b = cnt[0][b]+cnt[1][b], p_b = cnt[1][b]
//   S_b = sign(b) * (sum[0][b]+sum[1][b]) * 2^-24
//   tau_b = (I - Fp - p_b/2) / (n - F - c_b/2)
//   out = sum_b S_b*tau_b - e_max * I / n
// ---------------------------------------------------------------------------
__global__ __launch_bounds__(FIN_THREADS) void lovasz_final(
    const unsigned int* __restrict__ g_cnt, const unsigned long long* __restrict__ g_sum,
    const unsigned int* __restrict__ g_maxkey, float* __restrict__ out, int n)
{
    const int t = threadIdx.x;
    __shared__ unsigned int sc[FIN_THREADS], sp[FIN_THREADS];
    __shared__ double sd[FIN_THREADS];

    unsigned c[BPT], p[BPT];
    double sv[BPT];
    unsigned ct = 0, pt = 0;
    for (int k = 0; k < BPT; ++k) {
        const int b = t * BPT + k;
        unsigned c1 = g_cnt[VBUCKETS + b];
        c[k] = g_cnt[b] + c1;
        p[k] = c1;
        double mag = (double)(g_sum[b] + g_sum[VBUCKETS + b]) * (1.0 / 16777216.0);
        sv[k] = (b >= VBUCKETS / 2) ? mag : -mag;
        ct += c[k]; pt += p[k];
    }
    sc[t] = ct; sp[t] = pt;
    __syncthreads();

    // inclusive suffix scan over thread partials (Hillis-Steele)
    for (int off = 1; off < FIN_THREADS; off <<= 1) {
        unsigned a = (t + off < FIN_THREADS) ? sc[t + off] : 0u;
        unsigned b = (t + off < FIN_THREADS) ? sp[t + off] : 0u;
        __syncthreads();
        sc[t] += a; sp[t] += b;
        __syncthreads();
    }

    const unsigned I = sp[0];
    const double dn = (double)n;
    const double dI = (double)I;

    unsigned F  = sc[t] - ct;     // elements in strictly-higher threads' buckets
    unsigned Fp = sp[t] - pt;
    double acc = 0.0;
    for (int k = BPT - 1; k >= 0; --k) {
        if (c[k]) {
            const double tau = (dI - (double)Fp - 0.5 * (double)p[k])
                             / (dn - (double)F - 0.5 * (double)c[k]);
            acc += sv[k] * tau;
        }
        F += c[k]; Fp += p[k];
    }

    sd[t] = acc;
    __syncthreads();
    for (int off = FIN_THREADS / 2; off > 0; off >>= 1) {
        if (t < off) sd[t] += sd[t + off];
        __syncthreads();
    }

    if (t == 0) {
        unsigned mk = *g_maxkey;
        unsigned mu = (mk & 0x80000000u) ? (mk & 0x7FFFFFFFu) : ~mk;
        float emax = __uint_as_float(mu);
        out[0] = (float)(sd[0] - (double)emax * dI / dn);
    }
}

extern "C" void kernel_launch(void* const* d_in, const int* in_sizes, int n_in,
                              void* d_out, int out_size, void* d_ws, size_t ws_size,
                              hipStream_t stream)
{
    const float* logits  = (const float*)d_in[0];
    const int*   targets = (const int*)d_in[1];
    const int n = in_sizes[0];

    unsigned int* g_cnt = (unsigned int*)d_ws;
    unsigned long long* g_sum = (unsigned long long*)((char*)d_ws + CNT_BYTES);
    unsigned int* g_maxkey = (unsigned int*)((char*)d_ws + CNT_BYTES + SUM_BYTES);

    hipMemsetAsync(d_ws, 0, CNT_BYTES + SUM_BYTES + 256, stream);

    hipLaunchKernelGGL(lovasz_hist, dim3(512), dim3(1024), 0, stream,
                       logits, targets, g_cnt, g_sum, g_maxkey, n);
    hipLaunchKernelGGL(lovasz_final, dim3(1), dim3(1024), 0, stream,
                       g_cnt, g_sum, g_maxkey, (float*)d_out, n);
}